// Round 1
// baseline (6506.902 us; speedup 1.0000x reference)
//
#include <hip/hip_runtime.h>

#define F 256
#define TNB 16
#define NPB 4            // nodes per block, one wave per node
#define SLOPE 0.01f

// ---------------------------------------------------------------------------
// Scatter maps: map[node] = max row-index i with nodeset[i]==node (last-wins),
// -1 if node not in nodeset. atomicMax is order-independent -> deterministic.
// ---------------------------------------------------------------------------
__global__ void init_map_kernel(int* __restrict__ map, int n) {
    int i = blockIdx.x * blockDim.x + threadIdx.x;
    if (i < n) map[i] = -1;
}

__global__ void build_map_kernel(int* __restrict__ map, const int* __restrict__ nodeset, int n) {
    int i = blockIdx.x * blockDim.x + threadIdx.x;
    if (i < n) atomicMax(&map[nodeset[i]], i);
}

// ---------------------------------------------------------------------------
// Fused PinSage conv: gather -> (Q + leaky) -> weighted agg -> (W + leaky) -> L2norm
// USE_MAP: redirect reads of updated nodes to upd[map[node]] (layer 1).
// ---------------------------------------------------------------------------
template <bool USE_MAP>
__device__ __forceinline__ const float* row_ptr(int node, const float* __restrict__ h,
                                                const float* __restrict__ upd,
                                                const int* __restrict__ map) {
    if (USE_MAP) {
        int m = map[node];
        if (m >= 0) return upd + (size_t)m * F;
    }
    return h + (size_t)node * F;
}

template <bool USE_MAP>
__global__ __launch_bounds__(256, 2) void conv_kernel(
    const float* __restrict__ h, const float* __restrict__ upd, const int* __restrict__ map,
    const int* __restrict__ nodeset, const int* __restrict__ nb_nodes,
    const float* __restrict__ nb_w,
    const float* __restrict__ Qw, const float* __restrict__ Qb,
    const float* __restrict__ Ww, const float* __restrict__ Wb,
    float* __restrict__ out, int n)
{
    __shared__ float hnb[NPB][TNB][F];   // 64 KB
    __shared__ float hself[NPB][F];      // 4 KB
    __shared__ float hagg[NPB][F];       // 4 KB
    __shared__ float wsh[NPB][TNB];

    const int tid  = threadIdx.x;
    const int wave = tid >> 6;           // 0..3 == node within block
    const int lane = tid & 63;
    const int node_base = blockIdx.x * NPB;

    // ---- gather: 64 neighbor rows + 4 self rows, float4-coalesced ----
    #pragma unroll
    for (int i = 0; i < 16; ++i) {
        int r = i * 4 + wave;            // 0..63
        int nd = r >> 4, t = r & 15;
        int g = nb_nodes[(node_base + nd) * TNB + t];
        const float* src = row_ptr<USE_MAP>(g, h, upd, map);
        reinterpret_cast<float4*>(&hnb[nd][t][0])[lane] =
            reinterpret_cast<const float4*>(src)[lane];
    }
    {
        int g = nodeset[node_base + wave];
        const float* src = row_ptr<USE_MAP>(g, h, upd, map);
        reinterpret_cast<float4*>(&hself[wave][0])[lane] =
            reinterpret_cast<const float4*>(src)[lane];
    }
    if (tid < NPB * TNB) wsh[tid >> 4][tid & 15] = nb_w[node_base * TNB + tid];
    __syncthreads();

    const int nd = wave;

    // ---- Q matmul: lane owns features f_j = lane + 64*j, j=0..3 ----
    float acc[4][TNB];
    #pragma unroll
    for (int j = 0; j < 4; ++j)
        #pragma unroll
        for (int t = 0; t < TNB; ++t) acc[j][t] = 0.f;

    for (int k = 0; k < F; k += 4) {
        float4 q[4];
        #pragma unroll
        for (int j = 0; j < 4; ++j)
            q[j] = *reinterpret_cast<const float4*>(Qw + (size_t)(lane + 64 * j) * F + k);
        #pragma unroll
        for (int t = 0; t < TNB; ++t) {
            float4 hv = *reinterpret_cast<const float4*>(&hnb[nd][t][k]);
            #pragma unroll
            for (int j = 0; j < 4; ++j)
                acc[j][t] = fmaf(q[j].x, hv.x, fmaf(q[j].y, hv.y,
                             fmaf(q[j].z, hv.z, fmaf(q[j].w, hv.w, acc[j][t]))));
        }
    }

    // ---- bias + leaky + weighted aggregate ----
    float denom = 0.f;
    #pragma unroll
    for (int t = 0; t < TNB; ++t) denom += wsh[nd][t];
    if (denom == 0.f) denom = 1.f;
    float inv_d = 1.0f / denom;

    float qb[4];
    #pragma unroll
    for (int j = 0; j < 4; ++j) qb[j] = Qb[lane + 64 * j];

    float agg[4] = {0.f, 0.f, 0.f, 0.f};
    #pragma unroll
    for (int t = 0; t < TNB; ++t) {
        float wt = wsh[nd][t];
        #pragma unroll
        for (int j = 0; j < 4; ++j) {
            float v = acc[j][t] + qb[j];
            v = v > 0.f ? v : SLOPE * v;
            agg[j] = fmaf(wt, v, agg[j]);
        }
    }
    #pragma unroll
    for (int j = 0; j < 4; ++j) hagg[nd][lane + 64 * j] = agg[j] * inv_d;
    __syncthreads();

    // ---- W matmul over h_cat = [h_self | h_agg] (512) ----
    float wacc[4] = {0.f, 0.f, 0.f, 0.f};
    for (int k = 0; k < F; k += 4) {
        float4 hv = *reinterpret_cast<const float4*>(&hself[nd][k]);
        #pragma unroll
        for (int j = 0; j < 4; ++j) {
            float4 wv = *reinterpret_cast<const float4*>(Ww + (size_t)(lane + 64 * j) * (2 * F) + k);
            wacc[j] = fmaf(wv.x, hv.x, fmaf(wv.y, hv.y,
                        fmaf(wv.z, hv.z, fmaf(wv.w, hv.w, wacc[j]))));
        }
    }
    for (int k = 0; k < F; k += 4) {
        float4 hv = *reinterpret_cast<const float4*>(&hagg[nd][k]);
        #pragma unroll
        for (int j = 0; j < 4; ++j) {
            float4 wv = *reinterpret_cast<const float4*>(Ww + (size_t)(lane + 64 * j) * (2 * F) + F + k);
            wacc[j] = fmaf(wv.x, hv.x, fmaf(wv.y, hv.y,
                        fmaf(wv.z, hv.z, fmaf(wv.w, hv.w, wacc[j]))));
        }
    }

    // ---- bias + leaky + L2 normalize (wave-wide reduction over 256 feats) ----
    float nsq = 0.f;
    #pragma unroll
    for (int j = 0; j < 4; ++j) {
        float v = wacc[j] + Wb[lane + 64 * j];
        v = v > 0.f ? v : SLOPE * v;
        wacc[j] = v;
        nsq = fmaf(v, v, nsq);
    }
    #pragma unroll
    for (int m = 1; m < 64; m <<= 1) nsq += __shfl_xor(nsq, m, 64);
    float nrm = sqrtf(nsq);
    if (nrm == 0.f) nrm = 1.f;
    float inv_n = 1.0f / nrm;

    const size_t obase = (size_t)(node_base + nd) * F;
    #pragma unroll
    for (int j = 0; j < 4; ++j)
        out[obase + lane + 64 * j] = wacc[j] * inv_n;
}

// out[i] = new1[last j : nodeset1[j]==nodeset1[i]]  (post-scatter h[nodeset1])
__global__ void gather_out_kernel(float* __restrict__ out, const float* __restrict__ new1,
                                  const int* __restrict__ map1, const int* __restrict__ nodeset1) {
    int i = blockIdx.x;
    int f = threadIdx.x;
    int w = map1[nodeset1[i]];
    out[(size_t)i * F + f] = new1[(size_t)w * F + f];
}

extern "C" void kernel_launch(void* const* d_in, const int* in_sizes, int n_in,
                              void* d_out, int out_size, void* d_ws, size_t ws_size,
                              hipStream_t stream) {
    const float* h    = (const float*)d_in[0];
    const float* Q0w  = (const float*)d_in[1];
    const float* Q0b  = (const float*)d_in[2];
    const float* W0w  = (const float*)d_in[3];
    const float* W0b  = (const float*)d_in[4];
    const float* Q1w  = (const float*)d_in[5];
    const float* Q1b  = (const float*)d_in[6];
    const float* W1w  = (const float*)d_in[7];
    const float* W1b  = (const float*)d_in[8];
    const float* nbw0 = (const float*)d_in[9];
    const float* nbw1 = (const float*)d_in[10];
    const int* ns0    = (const int*)d_in[11];
    const int* nbn0   = (const int*)d_in[12];
    const int* ns1    = (const int*)d_in[13];
    const int* nbn1   = (const int*)d_in[14];

    const int L0 = in_sizes[11];        // 65536
    const int L1 = in_sizes[13];        // 4096
    const int NN = in_sizes[0] / F;     // 500000

    char* ws = (char*)d_ws;
    float* new0 = (float*)ws; ws += (size_t)L0 * F * sizeof(float);   // 64 MB
    float* new1 = (float*)ws; ws += (size_t)L1 * F * sizeof(float);   // 4 MB
    int* map0 = (int*)ws;     ws += (size_t)NN * sizeof(int);         // 2 MB
    int* map1 = (int*)ws;                                             // 2 MB

    init_map_kernel<<<(NN + 255) / 256, 256, 0, stream>>>(map0, NN);
    init_map_kernel<<<(NN + 255) / 256, 256, 0, stream>>>(map1, NN);
    build_map_kernel<<<(L0 + 255) / 256, 256, 0, stream>>>(map0, ns0, L0);
    build_map_kernel<<<(L1 + 255) / 256, 256, 0, stream>>>(map1, ns1, L1);

    // layer 0: reads original h only
    conv_kernel<false><<<L0 / NPB, 256, 0, stream>>>(
        h, nullptr, nullptr, ns0, nbn0, nbw0, Q0w, Q0b, W0w, W0b, new0, L0);
    // layer 1: reads h updated by layer-0 scatter (via map0 -> new0)
    conv_kernel<true><<<L1 / NPB, 256, 0, stream>>>(
        h, new0, map0, ns1, nbn1, nbw1, Q1w, Q1b, W1w, W1b, new1, L1);
    // final: h[nodeset1] after layer-1 scatter (duplicate-aware)
    gather_out_kernel<<<L1, 256, 0, stream>>>((float*)d_out, new1, map1, ns1);
}

// Round 2
// 2186.876 us; speedup vs baseline: 2.9754x; 2.9754x over previous
//
#include <hip/hip_runtime.h>

#define F 256
#define TNB 16
#define SLOPE 0.01f

typedef __attribute__((ext_vector_type(8))) short short8;
typedef __attribute__((ext_vector_type(4))) short short4v;
typedef __attribute__((ext_vector_type(4))) float f32x4;

__device__ __forceinline__ short f2b(float f) {
    unsigned u = __builtin_bit_cast(unsigned, f);
    u = (u + 0x7FFFu + ((u >> 16) & 1u)) >> 16;   // RNE, matches HW cvt
    return (short)u;
}

// ---------------------------------------------------------------------------
// scatter maps: map[node] = max i with nodeset[i]==node (last-wins), else -1
// ---------------------------------------------------------------------------
__global__ void init_map_kernel(int* __restrict__ map, int n) {
    int i = blockIdx.x * blockDim.x + threadIdx.x;
    if (i < n) map[i] = -1;
}
__global__ void build_map_kernel(int* __restrict__ map, const int* __restrict__ nodeset, int n) {
    int i = blockIdx.x * blockDim.x + threadIdx.x;
    if (i < n) atomicMax(&map[nodeset[i]], i);
}
__global__ void cvt_bf16_kernel(const float* __restrict__ src, short* __restrict__ dst, int n) {
    int i = blockIdx.x * blockDim.x + threadIdx.x;
    if (i < n) dst[i] = f2b(src[i]);
}

template <bool USE_MAP>
__device__ __forceinline__ const float* row_src(int g, const float* __restrict__ h,
                                                const float* __restrict__ upd,
                                                const int* __restrict__ map) {
    if constexpr (USE_MAP) {
        int m = map[g];
        if (m >= 0) return upd + (size_t)m * F;
    }
    return h + (size_t)g * F;
}

// ---------------------------------------------------------------------------
// Fused PinSage conv, bf16 MFMA. Block = 256 thr / 4 waves / 16 nodes.
// Round r: wave w owns node r*4+w — private gather + private Q-GEMM (no bar).
// W-phase: block-wide M=16 GEMM over Hcat=[self|agg] (K=512).
// ---------------------------------------------------------------------------
template <bool USE_MAP>
__global__ __launch_bounds__(256) void conv_mfma_kernel(
    const float* __restrict__ h, const float* __restrict__ upd, const int* __restrict__ map,
    const int* __restrict__ nodeset, const int* __restrict__ nb_nodes,
    const float* __restrict__ nb_w,
    const short* __restrict__ Qwb, const float* __restrict__ Qb,
    const short* __restrict__ Wwb, const float* __restrict__ Wb,
    float* __restrict__ out)
{
    // pads: row stride 264 (528B) / 520 (1040B) -> bank step 4 -> 2-way (free)
    __shared__ __align__(16) short Anb[4][TNB][264];   // per-wave nb rows, bf16
    __shared__ __align__(16) short Hcat[16][520];      // [self(256) | agg(256)]
    __shared__ float wsh[16][TNB];
    __shared__ float nsq_sh[16];

    const int tid  = threadIdx.x;
    const int wave = tid >> 6;
    const int lane = tid & 63;
    const int brow = lane & 15;    // frag row/col index
    const int kgrp = lane >> 4;    // 0..3
    const int nb_base = blockIdx.x * 16;

    wsh[tid >> 4][tid & 15] = nb_w[nb_base * TNB + tid];
    if (tid < 16) nsq_sh[tid] = 0.f;

    // hoisted per-lane biases
    float qb[16];
    #pragma unroll
    for (int n = 0; n < 16; ++n) qb[n] = Qb[n * 16 + brow];
    float wb[4];
    #pragma unroll
    for (int n2 = 0; n2 < 4; ++n2) wb[n2] = Wb[wave * 64 + n2 * 16 + brow];

    __syncthreads();   // wsh visible to all waves

    for (int rnd = 0; rnd < 4; ++rnd) {
        const int nl = rnd * 4 + wave;       // node-local 0..15
        const int gn = nb_base + nl;

        // ---- private gather: self + 16 neighbor rows, fp32 -> bf16 ----
        {
            int g = nodeset[gn];
            const float* src = row_src<USE_MAP>(g, h, upd, map);
            float4 v = reinterpret_cast<const float4*>(src)[lane];
            short4v b4; b4.x = f2b(v.x); b4.y = f2b(v.y); b4.z = f2b(v.z); b4.w = f2b(v.w);
            *reinterpret_cast<short4v*>(&Hcat[nl][lane * 4]) = b4;
        }
        #pragma unroll
        for (int t = 0; t < TNB; ++t) {
            int g = nb_nodes[gn * TNB + t];
            const float* src = row_src<USE_MAP>(g, h, upd, map);
            float4 v = reinterpret_cast<const float4*>(src)[lane];
            short4v b4; b4.x = f2b(v.x); b4.y = f2b(v.y); b4.z = f2b(v.z); b4.w = f2b(v.w);
            *reinterpret_cast<short4v*>(&Anb[wave][t][lane * 4]) = b4;
        }

        // ---- Q-GEMM: M=16 (t), N=256, K=256 ----
        f32x4 acc[16];
        #pragma unroll
        for (int n = 0; n < 16; ++n) acc[n] = (f32x4)0.f;

        for (int kk = 0; kk < 8; ++kk) {
            short8 a = *reinterpret_cast<const short8*>(&Anb[wave][brow][kk * 32 + kgrp * 8]);
            #pragma unroll
            for (int n = 0; n < 16; ++n) {
                short8 b = *reinterpret_cast<const short8*>(
                    Qwb + ((n * 16 + brow) << 8) + kk * 32 + kgrp * 8);
                acc[n] = __builtin_amdgcn_mfma_f32_16x16x32_bf16(a, b, acc[n], 0, 0, 0);
            }
        }

        // ---- bias + leaky + weighted agg (D: col=lane&15, row=(lane>>4)*4+reg) ----
        float denom = 0.f;
        #pragma unroll
        for (int t = 0; t < TNB; ++t) denom += wsh[nl][t];
        if (denom == 0.f) denom = 1.f;
        float inv_d = 1.0f / denom;
        float w4[4];
        #pragma unroll
        for (int r = 0; r < 4; ++r) w4[r] = wsh[nl][kgrp * 4 + r];

        #pragma unroll
        for (int n = 0; n < 16; ++n) {
            float p = 0.f;
            #pragma unroll
            for (int r = 0; r < 4; ++r) {
                float v = acc[n][r] + qb[n];
                v = v > 0.f ? v : SLOPE * v;
                p = fmaf(w4[r], v, p);
            }
            p += __shfl_xor(p, 16, 64);
            p += __shfl_xor(p, 32, 64);
            if (kgrp == 0) Hcat[nl][256 + n * 16 + brow] = f2b(p * inv_d);
        }
    }

    __syncthreads();   // Hcat complete

    // ---- W-GEMM: M=16 nodes, K=512, wave owns 64-col slice ----
    f32x4 acc2[4];
    #pragma unroll
    for (int n2 = 0; n2 < 4; ++n2) acc2[n2] = (f32x4)0.f;

    for (int kk = 0; kk < 16; ++kk) {
        short8 a = *reinterpret_cast<const short8*>(&Hcat[brow][kk * 32 + kgrp * 8]);
        #pragma unroll
        for (int n2 = 0; n2 < 4; ++n2) {
            short8 b = *reinterpret_cast<const short8*>(
                Wwb + ((wave * 64 + n2 * 16 + brow) << 9) + kk * 32 + kgrp * 8);
            acc2[n2] = __builtin_amdgcn_mfma_f32_16x16x32_bf16(a, b, acc2[n2], 0, 0, 0);
        }
    }

    // ---- bias + leaky + cross-wave L2 norm + store ----
    float vv[4][4];
    float ps[4] = {0.f, 0.f, 0.f, 0.f};
    #pragma unroll
    for (int n2 = 0; n2 < 4; ++n2)
        #pragma unroll
        for (int r = 0; r < 4; ++r) {
            float v = acc2[n2][r] + wb[n2];
            v = v > 0.f ? v : SLOPE * v;
            vv[n2][r] = v;
            ps[r] = fmaf(v, v, ps[r]);
        }
    #pragma unroll
    for (int m = 1; m < 16; m <<= 1)
        #pragma unroll
        for (int r = 0; r < 4; ++r) ps[r] += __shfl_xor(ps[r], m, 64);
    if (brow == 0) {
        #pragma unroll
        for (int r = 0; r < 4; ++r) atomicAdd(&nsq_sh[kgrp * 4 + r], ps[r]);
    }
    __syncthreads();

    #pragma unroll
    for (int r = 0; r < 4; ++r) {
        int node = kgrp * 4 + r;
        float nrm = sqrtf(nsq_sh[node]);
        if (nrm == 0.f) nrm = 1.f;
        float inv_n = 1.0f / nrm;
        #pragma unroll
        for (int n2 = 0; n2 < 4; ++n2)
            out[(size_t)(nb_base + node) * F + wave * 64 + n2 * 16 + brow] = vv[n2][r] * inv_n;
    }
}

// out[i] = new1[winner(nodeset1[i])]
__global__ void gather_out_kernel(float* __restrict__ out, const float* __restrict__ new1,
                                  const int* __restrict__ map1, const int* __restrict__ nodeset1) {
    int i = blockIdx.x;
    int f = threadIdx.x;
    int w = map1[nodeset1[i]];
    out[(size_t)i * F + f] = new1[(size_t)w * F + f];
}

extern "C" void kernel_launch(void* const* d_in, const int* in_sizes, int n_in,
                              void* d_out, int out_size, void* d_ws, size_t ws_size,
                              hipStream_t stream) {
    const float* h    = (const float*)d_in[0];
    const float* Q0w  = (const float*)d_in[1];
    const float* Q0b  = (const float*)d_in[2];
    const float* W0w  = (const float*)d_in[3];
    const float* W0b  = (const float*)d_in[4];
    const float* Q1w  = (const float*)d_in[5];
    const float* Q1b  = (const float*)d_in[6];
    const float* W1w  = (const float*)d_in[7];
    const float* W1b  = (const float*)d_in[8];
    const float* nbw0 = (const float*)d_in[9];
    const float* nbw1 = (const float*)d_in[10];
    const int* ns0    = (const int*)d_in[11];
    const int* nbn0   = (const int*)d_in[12];
    const int* ns1    = (const int*)d_in[13];
    const int* nbn1   = (const int*)d_in[14];

    const int L0 = in_sizes[11];        // 65536
    const int L1 = in_sizes[13];        // 4096
    const int NN = in_sizes[0] / F;     // 500000

    char* ws = (char*)d_ws;
    float* new0 = (float*)ws; ws += (size_t)L0 * F * sizeof(float);
    float* new1 = (float*)ws; ws += (size_t)L1 * F * sizeof(float);
    int* map0 = (int*)ws;     ws += (size_t)NN * sizeof(int);
    int* map1 = (int*)ws;     ws += (size_t)NN * sizeof(int);
    short* Q0wb = (short*)ws; ws += (size_t)F * F * sizeof(short);
    short* W0wb = (short*)ws; ws += (size_t)F * 2 * F * sizeof(short);
    short* Q1wb = (short*)ws; ws += (size_t)F * F * sizeof(short);
    short* W1wb = (short*)ws;

    init_map_kernel<<<(NN + 255) / 256, 256, 0, stream>>>(map0, NN);
    init_map_kernel<<<(NN + 255) / 256, 256, 0, stream>>>(map1, NN);
    build_map_kernel<<<(L0 + 255) / 256, 256, 0, stream>>>(map0, ns0, L0);
    build_map_kernel<<<(L1 + 255) / 256, 256, 0, stream>>>(map1, ns1, L1);
    cvt_bf16_kernel<<<(F * F + 255) / 256, 256, 0, stream>>>(Q0w, Q0wb, F * F);
    cvt_bf16_kernel<<<(F * 2 * F + 255) / 256, 256, 0, stream>>>(W0w, W0wb, F * 2 * F);
    cvt_bf16_kernel<<<(F * F + 255) / 256, 256, 0, stream>>>(Q1w, Q1wb, F * F);
    cvt_bf16_kernel<<<(F * 2 * F + 255) / 256, 256, 0, stream>>>(W1w, W1wb, F * 2 * F);

    conv_mfma_kernel<false><<<L0 / 16, 256, 0, stream>>>(
        h, nullptr, nullptr, ns0, nbn0, nbw0, Q0wb, Q0b, W0wb, W0b, new0);
    conv_mfma_kernel<true><<<L1 / 16, 256, 0, stream>>>(
        h, new0, map0, ns1, nbn1, nbw1, Q1wb, Q1b, W1wb, W1b, new1);
    gather_out_kernel<<<L1, 256, 0, stream>>>((float*)d_out, new1, map1, ns1);
}

// Round 3
// 1013.214 us; speedup vs baseline: 6.4220x; 2.1584x over previous
//
#include <hip/hip_runtime.h>

#define F 256
#define TNB 16
#define SLOPE 0.01f

typedef __attribute__((ext_vector_type(8))) short short8;
typedef __attribute__((ext_vector_type(4))) short short4v;
typedef __attribute__((ext_vector_type(4))) float f32x4;

__device__ __forceinline__ short f2b(float f) {
    unsigned u = __builtin_bit_cast(unsigned, f);
    u = (u + 0x7FFFu + ((u >> 16) & 1u)) >> 16;   // RNE
    return (short)u;
}

__device__ __forceinline__ void gld_lds16(const void* g, void* l) {
    __builtin_amdgcn_global_load_lds((const __attribute__((address_space(1))) void*)g,
                                     (__attribute__((address_space(3))) void*)l, 16, 0, 0);
}

// ---------------------------------------------------------------------------
__global__ void init_map_kernel(int* __restrict__ map, int n) {
    int i = blockIdx.x * blockDim.x + threadIdx.x;
    if (i < n) map[i] = -1;
}
__global__ void build_map_kernel(int* __restrict__ map, const int* __restrict__ nodeset, int n) {
    int i = blockIdx.x * blockDim.x + threadIdx.x;
    if (i < n) atomicMax(&map[nodeset[i]], i);
}
__global__ void cvt_bf16_kernel(const float* __restrict__ src, short* __restrict__ dst, int n) {
    int i = blockIdx.x * blockDim.x + threadIdx.x;
    if (i < n) dst[i] = f2b(src[i]);
}
// whole-table fp32 -> bf16, 8 elems/thread
__global__ void cvt_table_kernel(const float* __restrict__ src, short* __restrict__ dst, long n8) {
    long i = (long)blockIdx.x * blockDim.x + threadIdx.x;
    if (i < n8) {
        const float4* s = (const float4*)src + i * 2;
        float4 v0 = s[0], v1 = s[1];
        short8 o;
        o[0] = f2b(v0.x); o[1] = f2b(v0.y); o[2] = f2b(v0.z); o[3] = f2b(v0.w);
        o[4] = f2b(v1.x); o[5] = f2b(v1.y); o[6] = f2b(v1.z); o[7] = f2b(v1.w);
        ((short8*)dst)[i] = o;
    }
}
// scatter layer-0 results back into bf16 table (last-wins via map)
__global__ void scatter_cvt_kernel(const float* __restrict__ new0, const int* __restrict__ nodeset,
                                   const int* __restrict__ map, short* __restrict__ hb, int n) {
    int i = blockIdx.x * 4 + (threadIdx.x >> 6);
    int lane = threadIdx.x & 63;
    if (i >= n) return;
    int node = nodeset[i];
    if (map[node] != i) return;
    float4 v = *((const float4*)(new0 + (size_t)i * F) + lane);
    short4v o; o.x = f2b(v.x); o.y = f2b(v.y); o.z = f2b(v.z); o.w = f2b(v.w);
    *((short4v*)(hb + (size_t)node * F) + lane) = o;
}

// ---------------------------------------------------------------------------
// Fused PinSage conv. Block = 256 thr / 4 waves / 16 nodes, 8 rounds x 2 nodes.
// A-tiles staged bf16 global->LDS via global_load_lds, source-swizzled
// (slot ^= row&7 per 16B) so ds_read_b128 is bank-spread on linear LDS.
// Q-GEMM: block-wide M=32, wave owns 64-col slice (B traffic /4).
// ---------------------------------------------------------------------------
__global__ __launch_bounds__(256, 3) void conv_mfma_kernel(
    const short* __restrict__ hb,
    const int* __restrict__ nodeset, const int* __restrict__ nb_nodes,
    const float* __restrict__ nb_w,
    const short* __restrict__ Qwb, const float* __restrict__ Qb,
    const short* __restrict__ Wwb, const float* __restrict__ Wb,
    float* __restrict__ out)
{
    __shared__ __align__(16) short Abuf[2][32][256];   // 2 x 16KB, swizzled storage
    __shared__ __align__(16) short Hself[16][256];     // 8KB, swizzled storage
    __shared__ __align__(16) short Hagg[16][264];      // padded (528B stride)
    __shared__ float wsh[16][16];
    __shared__ float nsq_sh[16];

    const int tid  = threadIdx.x;
    const int wave = tid >> 6;
    const int lane = tid & 63;
    const int brow = lane & 15;
    const int kgrp = lane >> 4;
    const int nb_base = blockIdx.x * 16;

    wsh[tid >> 4][tid & 15] = nb_w[nb_base * TNB + tid];
    if (tid < 16) nsq_sh[tid] = 0.f;

    float qb[4], wb[4];
    #pragma unroll
    for (int ni = 0; ni < 4; ++ni) {
        qb[ni] = Qb[wave * 64 + ni * 16 + brow];
        wb[ni] = Wb[wave * 64 + ni * 16 + brow];
    }

    const int half = lane >> 5;       // 0/1 within the 2-row chunk
    const int p    = lane & 31;       // 16B slot within row

    // stage round t's A rows (32) + self rows (2) into buf b
    auto stage = [&](int b, int t) {
        const int idb = (nb_base + t * 2) * TNB;
        char* abase = (char*)&Abuf[b][0][0];
        #pragma unroll
        for (int i = 0; i < 4; ++i) {
            int c = wave * 4 + i;               // chunk 0..15 = rows 2c,2c+1
            int r = 2 * c + half;
            int g = nb_nodes[idb + r];
            const char* src = (const char*)hb + ((size_t)g << 9) + ((p ^ (r & 7)) << 4);
            gld_lds16(src, abase + c * 1024);
        }
        if (wave == 0) {
            int r2 = t * 2 + half;
            int g = nodeset[nb_base + r2];
            const char* src = (const char*)hb + ((size_t)g << 9) + ((p ^ (r2 & 7)) << 4);
            gld_lds16(src, (char*)&Hself[0][0] + t * 1024);
        }
    };

    stage(0, 0);
    __syncthreads();

    for (int rnd = 0; rnd < 8; ++rnd) {
        const int b = rnd & 1;
        if (rnd < 7) stage(b ^ 1, rnd + 1);     // async prefetch, drains at barrier

        // ---- Q-GEMM: M=32 (2 nodes x 16 t), N=64 (wave slice), K=256 ----
        const char* ab = (const char*)&Abuf[b][0][0];
        f32x4 acc[2][4];
        #pragma unroll
        for (int mi = 0; mi < 2; ++mi)
            #pragma unroll
            for (int ni = 0; ni < 4; ++ni) acc[mi][ni] = (f32x4)0.f;

        #pragma unroll
        for (int kk = 0; kk < 8; ++kk) {
            const int sx = ((kk * 4 + kgrp) ^ (brow & 7)) << 4;   // swizzled 16B slot
            short8 a0 = *(const short8*)(ab + brow * 512 + sx);
            short8 a1 = *(const short8*)(ab + (16 + brow) * 512 + sx);
            #pragma unroll
            for (int ni = 0; ni < 4; ++ni) {
                short8 bb = *(const short8*)(
                    Qwb + (((size_t)(wave * 64 + ni * 16 + brow)) << 8) + kk * 32 + kgrp * 8);
                acc[0][ni] = __builtin_amdgcn_mfma_f32_16x16x32_bf16(a0, bb, acc[0][ni], 0, 0, 0);
                acc[1][ni] = __builtin_amdgcn_mfma_f32_16x16x32_bf16(a1, bb, acc[1][ni], 0, 0, 0);
            }
        }

        // ---- bias + leaky + weighted agg; D: row=t=(kgrp*4+r), col=ni*16+brow ----
        #pragma unroll
        for (int mi = 0; mi < 2; ++mi) {
            const int nl = rnd * 2 + mi;
            float denom = 0.f;
            #pragma unroll
            for (int t = 0; t < TNB; ++t) denom += wsh[nl][t];
            if (denom == 0.f) denom = 1.f;
            float inv_d = 1.0f / denom;
            float w4[4];
            #pragma unroll
            for (int r = 0; r < 4; ++r) w4[r] = wsh[nl][kgrp * 4 + r];
            #pragma unroll
            for (int ni = 0; ni < 4; ++ni) {
                float pacc = 0.f;
                #pragma unroll
                for (int r = 0; r < 4; ++r) {
                    float v = acc[mi][ni][r] + qb[ni];
                    v = v > 0.f ? v : SLOPE * v;
                    pacc = fmaf(w4[r], v, pacc);
                }
                pacc += __shfl_xor(pacc, 16, 64);
                pacc += __shfl_xor(pacc, 32, 64);
                if (kgrp == 0) Hagg[nl][wave * 64 + ni * 16 + brow] = f2b(pacc * inv_d);
            }
        }
        __syncthreads();   // next buf landed + Hagg row visible later
    }

    // ---- W-GEMM: M=16 nodes, N=64 (wave slice), K=512 = [self | agg] ----
    f32x4 acc2[4];
    #pragma unroll
    for (int ni = 0; ni < 4; ++ni) acc2[ni] = (f32x4)0.f;

    #pragma unroll
    for (int kk = 0; kk < 8; ++kk) {           // K-half 0: Hself (swizzled)
        const int sx = ((kk * 4 + kgrp) ^ (brow & 7)) << 4;
        short8 a = *(const short8*)((const char*)&Hself[0][0] + brow * 512 + sx);
        #pragma unroll
        for (int ni = 0; ni < 4; ++ni) {
            short8 bb = *(const short8*)(
                Wwb + (((size_t)(wave * 64 + ni * 16 + brow)) << 9) + kk * 32 + kgrp * 8);
            acc2[ni] = __builtin_amdgcn_mfma_f32_16x16x32_bf16(a, bb, acc2[ni], 0, 0, 0);
        }
    }
    #pragma unroll
    for (int kk = 0; kk < 8; ++kk) {           // K-half 1: Hagg (padded)
        short8 a = *(const short8*)(&Hagg[brow][kk * 32 + kgrp * 8]);
        #pragma unroll
        for (int ni = 0; ni < 4; ++ni) {
            short8 bb = *(const short8*)(
                Wwb + (((size_t)(wave * 64 + ni * 16 + brow)) << 9) + 256 + kk * 32 + kgrp * 8);
            acc2[ni] = __builtin_amdgcn_mfma_f32_16x16x32_bf16(a, bb, acc2[ni], 0, 0, 0);
        }
    }

    // ---- bias + leaky + L2 norm + store; D row = node = kgrp*4+r ----
    float vv[4][4];
    float ps[4] = {0.f, 0.f, 0.f, 0.f};
    #pragma unroll
    for (int ni = 0; ni < 4; ++ni)
        #pragma unroll
        for (int r = 0; r < 4; ++r) {
            float v = acc2[ni][r] + wb[ni];
            v = v > 0.f ? v : SLOPE * v;
            vv[ni][r] = v;
            ps[r] = fmaf(v, v, ps[r]);
        }
    #pragma unroll
    for (int m = 1; m < 16; m <<= 1)
        #pragma unroll
        for (int r = 0; r < 4; ++r) ps[r] += __shfl_xor(ps[r], m, 64);
    if (brow == 0) {
        #pragma unroll
        for (int r = 0; r < 4; ++r) atomicAdd(&nsq_sh[kgrp * 4 + r], ps[r]);
    }
    __syncthreads();

    #pragma unroll
    for (int r = 0; r < 4; ++r) {
        int node = kgrp * 4 + r;
        float nrm = sqrtf(nsq_sh[node]);
        if (nrm == 0.f) nrm = 1.f;
        float inv_n = 1.0f / nrm;
        #pragma unroll
        for (int ni = 0; ni < 4; ++ni)
            out[(size_t)(nb_base + node) * F + wave * 64 + ni * 16 + brow] = vv[ni][r] * inv_n;
    }
}

__global__ void gather_out_kernel(float* __restrict__ out, const float* __restrict__ new1,
                                  const int* __restrict__ map1, const int* __restrict__ nodeset1) {
    int i = blockIdx.x;
    int f = threadIdx.x;
    int w = map1[nodeset1[i]];
    out[(size_t)i * F + f] = new1[(size_t)w * F + f];
}

extern "C" void kernel_launch(void* const* d_in, const int* in_sizes, int n_in,
                              void* d_out, int out_size, void* d_ws, size_t ws_size,
                              hipStream_t stream) {
    const float* h    = (const float*)d_in[0];
    const float* Q0w  = (const float*)d_in[1];
    const float* Q0b  = (const float*)d_in[2];
    const float* W0w  = (const float*)d_in[3];
    const float* W0b  = (const float*)d_in[4];
    const float* Q1w  = (const float*)d_in[5];
    const float* Q1b  = (const float*)d_in[6];
    const float* W1w  = (const float*)d_in[7];
    const float* W1b  = (const float*)d_in[8];
    const float* nbw0 = (const float*)d_in[9];
    const float* nbw1 = (const float*)d_in[10];
    const int* ns0    = (const int*)d_in[11];
    const int* nbn0   = (const int*)d_in[12];
    const int* ns1    = (const int*)d_in[13];
    const int* nbn1   = (const int*)d_in[14];

    const int L0 = in_sizes[11];        // 65536
    const int L1 = in_sizes[13];        // 4096
    const int NN = in_sizes[0] / F;     // 500000

    char* ws = (char*)d_ws;
    short* hb   = (short*)ws; ws += (size_t)NN * F * sizeof(short);   // 256 MB bf16 table
    float* new0 = (float*)ws; ws += (size_t)L0 * F * sizeof(float);   // 64 MB
    float* new1 = (float*)ws; ws += (size_t)L1 * F * sizeof(float);   // 4 MB
    int* map0 = (int*)ws;     ws += (size_t)NN * sizeof(int);
    int* map1 = (int*)ws;     ws += (size_t)NN * sizeof(int);
    short* Q0wb = (short*)ws; ws += (size_t)F * F * sizeof(short);
    short* W0wb = (short*)ws; ws += (size_t)F * 2 * F * sizeof(short);
    short* Q1wb = (short*)ws; ws += (size_t)F * F * sizeof(short);
    short* W1wb = (short*)ws;

    long n8 = (long)NN * F / 8;
    cvt_table_kernel<<<(int)((n8 + 255) / 256), 256, 0, stream>>>(h, hb, n8);
    init_map_kernel<<<(NN + 255) / 256, 256, 0, stream>>>(map0, NN);
    init_map_kernel<<<(NN + 255) / 256, 256, 0, stream>>>(map1, NN);
    build_map_kernel<<<(L0 + 255) / 256, 256, 0, stream>>>(map0, ns0, L0);
    build_map_kernel<<<(L1 + 255) / 256, 256, 0, stream>>>(map1, ns1, L1);
    cvt_bf16_kernel<<<(F * F + 255) / 256, 256, 0, stream>>>(Q0w, Q0wb, F * F);
    cvt_bf16_kernel<<<(F * 2 * F + 255) / 256, 256, 0, stream>>>(W0w, W0wb, F * 2 * F);
    cvt_bf16_kernel<<<(F * F + 255) / 256, 256, 0, stream>>>(Q1w, Q1wb, F * F);
    cvt_bf16_kernel<<<(F * 2 * F + 255) / 256, 256, 0, stream>>>(W1w, W1wb, F * 2 * F);

    conv_mfma_kernel<<<L0 / 16, 256, 0, stream>>>(
        hb, ns0, nbn0, nbw0, Q0wb, Q0b, W0wb, W0b, new0);
    scatter_cvt_kernel<<<(L0 + 3) / 4, 256, 0, stream>>>(new0, ns0, map0, hb, L0);
    conv_mfma_kernel<<<L1 / 16, 256, 0, stream>>>(
        hb, ns1, nbn1, nbw1, Q1wb, Q1b, W1wb, W1b, new1);
    gather_out_kernel<<<L1, 256, 0, stream>>>((float*)d_out, new1, map1, ns1);
}

// Round 4
// 591.196 us; speedup vs baseline: 11.0063x; 1.7138x over previous
//
#include <hip/hip_runtime.h>

#define F 256
#define TNB 16
#define SLOPE 0.01f

typedef __attribute__((ext_vector_type(8))) short short8;
typedef __attribute__((ext_vector_type(4))) short short4v;
typedef __attribute__((ext_vector_type(4))) float f32x4;

__device__ __forceinline__ short f2b(float f) {
    unsigned u = __builtin_bit_cast(unsigned, f);
    u = (u + 0x7FFFu + ((u >> 16) & 1u)) >> 16;   // RNE
    return (short)u;
}

__device__ __forceinline__ void gld_lds16(const void* g, void* l) {
    __builtin_amdgcn_global_load_lds((const __attribute__((address_space(1))) void*)g,
                                     (__attribute__((address_space(3))) void*)l, 16, 0, 0);
}

// ---------------------------------------------------------------------------
__global__ void init_map_kernel(int* __restrict__ map, int n) {
    int i = blockIdx.x * blockDim.x + threadIdx.x;
    if (i < n) map[i] = -1;
}
__global__ void build_map_kernel(int* __restrict__ map, const int* __restrict__ nodeset, int n) {
    int i = blockIdx.x * blockDim.x + threadIdx.x;
    if (i < n) atomicMax(&map[nodeset[i]], i);
}
__global__ void cvt_bf16_kernel(const float* __restrict__ src, short* __restrict__ dst, int n) {
    int i = blockIdx.x * blockDim.x + threadIdx.x;
    if (i < n) dst[i] = f2b(src[i]);
}
// whole-table fp32 -> bf16, 8 elems/thread
__global__ void cvt_table_kernel(const float* __restrict__ src, short* __restrict__ dst, long n8) {
    long i = (long)blockIdx.x * blockDim.x + threadIdx.x;
    if (i < n8) {
        const float4* s = (const float4*)src + i * 2;
        float4 v0 = s[0], v1 = s[1];
        short8 o;
        o[0] = f2b(v0.x); o[1] = f2b(v0.y); o[2] = f2b(v0.z); o[3] = f2b(v0.w);
        o[4] = f2b(v1.x); o[5] = f2b(v1.y); o[6] = f2b(v1.z); o[7] = f2b(v1.w);
        ((short8*)dst)[i] = o;
    }
}
// scatter layer-0 results back into bf16 table (last-wins via map)
__global__ void scatter_cvt_kernel(const float* __restrict__ new0, const int* __restrict__ nodeset,
                                   const int* __restrict__ map, short* __restrict__ hb, int n) {
    int i = blockIdx.x * 4 + (threadIdx.x >> 6);
    int lane = threadIdx.x & 63;
    if (i >= n) return;
    int node = nodeset[i];
    if (map[node] != i) return;
    float4 v = *((const float4*)(new0 + (size_t)i * F) + lane);
    short4v o; o.x = f2b(v.x); o.y = f2b(v.y); o.z = f2b(v.z); o.w = f2b(v.w);
    *((short4v*)(hb + (size_t)node * F) + lane) = o;
}

// ---------------------------------------------------------------------------
// Fused PinSage conv. Block = 256 thr / 4 waves / 16 nodes, 8 rounds x 2 nodes.
// A staged bf16 global->LDS (global_load_lds), source-swizzled (slot ^= row&7
// per 16B, within-128B permutation -> coalescing intact).
// Q B-slice (wave's 64 cols, K=256) preloaded to 128 VGPRs once -> inner loop
// is pure ds_read_b128 + MFMA.
// ---------------------------------------------------------------------------
__global__ __launch_bounds__(256, 2) void conv_mfma_kernel(
    const short* __restrict__ hb,
    const int* __restrict__ nodeset, const int* __restrict__ nb_nodes,
    const float* __restrict__ nb_w,
    const short* __restrict__ Qwb, const float* __restrict__ Qb,
    const short* __restrict__ Wwb, const float* __restrict__ Wb,
    float* __restrict__ out)
{
    __shared__ __align__(16) short Abuf[2][32][256];   // 2 x 16KB, swizzled storage
    __shared__ __align__(16) short Hself[16][256];     // 8KB, swizzled storage
    __shared__ __align__(16) short Hagg[16][264];      // padded (528B stride)
    __shared__ float wsh[16][16];
    __shared__ float nsq_sh[16];

    const int tid  = threadIdx.x;
    const int wave = tid >> 6;
    const int lane = tid & 63;
    const int brow = lane & 15;
    const int kgrp = lane >> 4;
    const int nb_base = blockIdx.x * 16;

    wsh[tid >> 4][tid & 15] = nb_w[nb_base * TNB + tid];
    if (tid < 16) nsq_sh[tid] = 0.f;

    float qb[4], wb[4];
    #pragma unroll
    for (int ni = 0; ni < 4; ++ni) {
        qb[ni] = Qb[wave * 64 + ni * 16 + brow];
        wb[ni] = Wb[wave * 64 + ni * 16 + brow];
    }

    const int half = lane >> 5;       // 0/1 within the 2-row chunk
    const int p    = lane & 31;       // 16B slot within row

    // stage round t's A rows (32) + self rows (2) into buf b
    auto stage = [&](int b, int t) {
        const int idb = (nb_base + t * 2) * TNB;
        char* abase = (char*)&Abuf[b][0][0];
        #pragma unroll
        for (int i = 0; i < 4; ++i) {
            int c = wave * 4 + i;               // chunk 0..15 = rows 2c,2c+1
            int r = 2 * c + half;
            int g = nb_nodes[idb + r];
            const char* src = (const char*)hb + ((size_t)g << 9) + ((p ^ (r & 7)) << 4);
            gld_lds16(src, abase + c * 1024);
        }
        if (wave == 0) {
            int r2 = t * 2 + half;
            int g = nodeset[nb_base + r2];
            const char* src = (const char*)hb + ((size_t)g << 9) + ((p ^ (r2 & 7)) << 4);
            gld_lds16(src, (char*)&Hself[0][0] + t * 1024);
        }
    };

    stage(0, 0);

    // ---- preload wave's Q B-slice: 32 frags = 128 VGPRs, static indexing ----
    short8 bq[8][4];
    #pragma unroll
    for (int kk = 0; kk < 8; ++kk)
        #pragma unroll
        for (int ni = 0; ni < 4; ++ni)
            bq[kk][ni] = *(const short8*)(
                Qwb + (((size_t)(wave * 64 + ni * 16 + brow)) << 8) + kk * 32 + kgrp * 8);

    __syncthreads();

    for (int rnd = 0; rnd < 8; ++rnd) {
        const int b = rnd & 1;
        if (rnd < 7) stage(b ^ 1, rnd + 1);     // async prefetch, drains at barrier

        // ---- Q-GEMM: M=32 (2 nodes x 16 t), N=64 (wave slice), K=256 ----
        const char* ab = (const char*)&Abuf[b][0][0];
        f32x4 acc[2][4];
        #pragma unroll
        for (int mi = 0; mi < 2; ++mi)
            #pragma unroll
            for (int ni = 0; ni < 4; ++ni) acc[mi][ni] = (f32x4)0.f;

        #pragma unroll
        for (int kk = 0; kk < 8; ++kk) {
            const int sx = ((kk * 4 + kgrp) ^ (brow & 7)) << 4;   // swizzled 16B slot
            short8 a0 = *(const short8*)(ab + brow * 512 + sx);
            short8 a1 = *(const short8*)(ab + (16 + brow) * 512 + sx);
            #pragma unroll
            for (int ni = 0; ni < 4; ++ni) {
                acc[0][ni] = __builtin_amdgcn_mfma_f32_16x16x32_bf16(a0, bq[kk][ni], acc[0][ni], 0, 0, 0);
                acc[1][ni] = __builtin_amdgcn_mfma_f32_16x16x32_bf16(a1, bq[kk][ni], acc[1][ni], 0, 0, 0);
            }
        }

        // ---- bias + leaky + weighted agg; D: row=t=(kgrp*4+r), col=ni*16+brow ----
        #pragma unroll
        for (int mi = 0; mi < 2; ++mi) {
            const int nl = rnd * 2 + mi;
            float denom = 0.f;
            #pragma unroll
            for (int t = 0; t < TNB; ++t) denom += wsh[nl][t];
            if (denom == 0.f) denom = 1.f;
            float inv_d = 1.0f / denom;
            float w4[4];
            #pragma unroll
            for (int r = 0; r < 4; ++r) w4[r] = wsh[nl][kgrp * 4 + r];
            #pragma unroll
            for (int ni = 0; ni < 4; ++ni) {
                float pacc = 0.f;
                #pragma unroll
                for (int r = 0; r < 4; ++r) {
                    float v = acc[mi][ni][r] + qb[ni];
                    v = v > 0.f ? v : SLOPE * v;
                    pacc = fmaf(w4[r], v, pacc);
                }
                pacc += __shfl_xor(pacc, 16, 64);
                pacc += __shfl_xor(pacc, 32, 64);
                if (kgrp == 0) Hagg[nl][wave * 64 + ni * 16 + brow] = f2b(pacc * inv_d);
            }
        }
        __syncthreads();   // next buf landed + Hagg row published
    }

    // ---- W-GEMM: M=16 nodes, N=64 (wave slice), K=512 = [self | agg] ----
    f32x4 acc2[4];
    #pragma unroll
    for (int ni = 0; ni < 4; ++ni) acc2[ni] = (f32x4)0.f;

    #pragma unroll
    for (int kk = 0; kk < 8; ++kk) {           // K-half 0: Hself (swizzled)
        const int sx = ((kk * 4 + kgrp) ^ (brow & 7)) << 4;
        short8 a = *(const short8*)((const char*)&Hself[0][0] + brow * 512 + sx);
        #pragma unroll
        for (int ni = 0; ni < 4; ++ni) {
            short8 bb = *(const short8*)(
                Wwb + (((size_t)(wave * 64 + ni * 16 + brow)) << 9) + kk * 32 + kgrp * 8);
            acc2[ni] = __builtin_amdgcn_mfma_f32_16x16x32_bf16(a, bb, acc2[ni], 0, 0, 0);
        }
    }
    #pragma unroll
    for (int kk = 0; kk < 8; ++kk) {           // K-half 1: Hagg (padded)
        short8 a = *(const short8*)(&Hagg[brow][kk * 32 + kgrp * 8]);
        #pragma unroll
        for (int ni = 0; ni < 4; ++ni) {
            short8 bb = *(const short8*)(
                Wwb + (((size_t)(wave * 64 + ni * 16 + brow)) << 9) + 256 + kk * 32 + kgrp * 8);
            acc2[ni] = __builtin_amdgcn_mfma_f32_16x16x32_bf16(a, bb, acc2[ni], 0, 0, 0);
        }
    }

    // ---- bias + leaky + L2 norm + store; D row = node = kgrp*4+r ----
    float vv[4][4];
    float ps[4] = {0.f, 0.f, 0.f, 0.f};
    #pragma unroll
    for (int ni = 0; ni < 4; ++ni)
        #pragma unroll
        for (int r = 0; r < 4; ++r) {
            float v = acc2[ni][r] + wb[ni];
            v = v > 0.f ? v : SLOPE * v;
            vv[ni][r] = v;
            ps[r] = fmaf(v, v, ps[r]);
        }
    #pragma unroll
    for (int m = 1; m < 16; m <<= 1)
        #pragma unroll
        for (int r = 0; r < 4; ++r) ps[r] += __shfl_xor(ps[r], m, 64);
    if (brow == 0) {
        #pragma unroll
        for (int r = 0; r < 4; ++r) atomicAdd(&nsq_sh[kgrp * 4 + r], ps[r]);
    }
    __syncthreads();

    #pragma unroll
    for (int r = 0; r < 4; ++r) {
        int node = kgrp * 4 + r;
        float nrm = sqrtf(nsq_sh[node]);
        if (nrm == 0.f) nrm = 1.f;
        float inv_n = 1.0f / nrm;
        #pragma unroll
        for (int ni = 0; ni < 4; ++ni)
            out[(size_t)(nb_base + node) * F + wave * 64 + ni * 16 + brow] = vv[ni][r] * inv_n;
    }
}

__global__ void gather_out_kernel(float* __restrict__ out, const float* __restrict__ new1,
                                  const int* __restrict__ map1, const int* __restrict__ nodeset1) {
    int i = blockIdx.x;
    int f = threadIdx.x;
    int w = map1[nodeset1[i]];
    out[(size_t)i * F + f] = new1[(size_t)w * F + f];
}

extern "C" void kernel_launch(void* const* d_in, const int* in_sizes, int n_in,
                              void* d_out, int out_size, void* d_ws, size_t ws_size,
                              hipStream_t stream) {
    const float* h    = (const float*)d_in[0];
    const float* Q0w  = (const float*)d_in[1];
    const float* Q0b  = (const float*)d_in[2];
    const float* W0w  = (const float*)d_in[3];
    const float* W0b  = (const float*)d_in[4];
    const float* Q1w  = (const float*)d_in[5];
    const float* Q1b  = (const float*)d_in[6];
    const float* W1w  = (const float*)d_in[7];
    const float* W1b  = (const float*)d_in[8];
    const float* nbw0 = (const float*)d_in[9];
    const float* nbw1 = (const float*)d_in[10];
    const int* ns0    = (const int*)d_in[11];
    const int* nbn0   = (const int*)d_in[12];
    const int* ns1    = (const int*)d_in[13];
    const int* nbn1   = (const int*)d_in[14];

    const int L0 = in_sizes[11];        // 65536
    const int L1 = in_sizes[13];        // 4096
    const int NN = in_sizes[0] / F;     // 500000

    char* ws = (char*)d_ws;
    short* hb   = (short*)ws; ws += (size_t)NN * F * sizeof(short);   // 256 MB bf16 table
    float* new0 = (float*)ws; ws += (size_t)L0 * F * sizeof(float);   // 64 MB
    float* new1 = (float*)ws; ws += (size_t)L1 * F * sizeof(float);   // 4 MB
    int* map0 = (int*)ws;     ws += (size_t)NN * sizeof(int);
    int* map1 = (int*)ws;     ws += (size_t)NN * sizeof(int);
    short* Q0wb = (short*)ws; ws += (size_t)F * F * sizeof(short);
    short* W0wb = (short*)ws; ws += (size_t)F * 2 * F * sizeof(short);
    short* Q1wb = (short*)ws; ws += (size_t)F * F * sizeof(short);
    short* W1wb = (short*)ws;

    long n8 = (long)NN * F / 8;
    cvt_table_kernel<<<(int)((n8 + 255) / 256), 256, 0, stream>>>(h, hb, n8);
    init_map_kernel<<<(NN + 255) / 256, 256, 0, stream>>>(map0, NN);
    init_map_kernel<<<(NN + 255) / 256, 256, 0, stream>>>(map1, NN);
    build_map_kernel<<<(L0 + 255) / 256, 256, 0, stream>>>(map0, ns0, L0);
    build_map_kernel<<<(L1 + 255) / 256, 256, 0, stream>>>(map1, ns1, L1);
    cvt_bf16_kernel<<<(F * F + 255) / 256, 256, 0, stream>>>(Q0w, Q0wb, F * F);
    cvt_bf16_kernel<<<(F * 2 * F + 255) / 256, 256, 0, stream>>>(W0w, W0wb, F * 2 * F);
    cvt_bf16_kernel<<<(F * F + 255) / 256, 256, 0, stream>>>(Q1w, Q1wb, F * F);
    cvt_bf16_kernel<<<(F * 2 * F + 255) / 256, 256, 0, stream>>>(W1w, W1wb, F * 2 * F);

    conv_mfma_kernel<<<L0 / 16, 256, 0, stream>>>(
        hb, ns0, nbn0, nbw0, Q0wb, Q0b, W0wb, W0b, new0);
    scatter_cvt_kernel<<<(L0 + 3) / 4, 256, 0, stream>>>(new0, ns0, map0, hb, L0);
    conv_mfma_kernel<<<L1 / 16, 256, 0, stream>>>(
        hb, ns1, nbn1, nbw1, Q1wb, Q1b, W1wb, W1b, new1);
    gather_out_kernel<<<L1, 256, 0, stream>>>((float*)d_out, new1, map1, ns1);
}

// Round 5
// 502.529 us; speedup vs baseline: 12.9483x; 1.1764x over previous
//
#include <hip/hip_runtime.h>

#define F 256
#define TNB 16
#define SLOPE 0.01f

typedef __attribute__((ext_vector_type(8))) short short8;
typedef __attribute__((ext_vector_type(4))) short short4v;
typedef __attribute__((ext_vector_type(4))) float f32x4;

__device__ __forceinline__ short f2b(float f) {
    unsigned u = __builtin_bit_cast(unsigned, f);
    u = (u + 0x7FFFu + ((u >> 16) & 1u)) >> 16;   // RNE
    return (short)u;
}

// ---------------------------------------------------------------------------
__global__ void init_map_kernel(int* __restrict__ map, int n) {
    int i = blockIdx.x * blockDim.x + threadIdx.x;
    if (i < n) map[i] = -1;
}
__global__ void build_map_kernel(int* __restrict__ map, const int* __restrict__ nodeset, int n) {
    int i = blockIdx.x * blockDim.x + threadIdx.x;
    if (i < n) atomicMax(&map[nodeset[i]], i);
}
__global__ void cvt_bf16_kernel(const float* __restrict__ src, short* __restrict__ dst, int n) {
    int i = blockIdx.x * blockDim.x + threadIdx.x;
    if (i < n) dst[i] = f2b(src[i]);
}
__global__ void cvt_table_kernel(const float* __restrict__ src, short* __restrict__ dst, long n8) {
    long i = (long)blockIdx.x * blockDim.x + threadIdx.x;
    if (i < n8) {
        const float4* s = (const float4*)src + i * 2;
        float4 v0 = s[0], v1 = s[1];
        short8 o;
        o[0] = f2b(v0.x); o[1] = f2b(v0.y); o[2] = f2b(v0.z); o[3] = f2b(v0.w);
        o[4] = f2b(v1.x); o[5] = f2b(v1.y); o[6] = f2b(v1.z); o[7] = f2b(v1.w);
        ((short8*)dst)[i] = o;
    }
}
__global__ void scatter_cvt_kernel(const float* __restrict__ new0, const int* __restrict__ nodeset,
                                   const int* __restrict__ map, short* __restrict__ hb, int n) {
    int i = blockIdx.x * 4 + (threadIdx.x >> 6);
    int lane = threadIdx.x & 63;
    if (i >= n) return;
    int node = nodeset[i];
    if (map[node] != i) return;
    float4 v = *((const float4*)(new0 + (size_t)i * F) + lane);
    short4v o; o.x = f2b(v.x); o.y = f2b(v.y); o.z = f2b(v.z); o.w = f2b(v.w);
    *((short4v*)(hb + (size_t)node * F) + lane) = o;
}

// ---------------------------------------------------------------------------
// Fused PinSage conv. Block = 256 thr / 4 waves / 16 nodes, 8 rounds x 2 nodes.
// Reg-staged pipeline (T14): per round, issue idx(r+2) + row loads(r+1)->VGPR
// BEFORE the GEMM; ds_write (XOR-swizzled) AFTER it -> compiler vmcnt waits
// land for free; __syncthreads drains nothing.
// ---------------------------------------------------------------------------
__global__ __launch_bounds__(256, 2) void conv_mfma_kernel(
    const short* __restrict__ hb,
    const int* __restrict__ nodeset, const int* __restrict__ nb_nodes,
    const float* __restrict__ nb_w,
    const short* __restrict__ Qwb, const float* __restrict__ Qb,
    const short* __restrict__ Wwb, const float* __restrict__ Wb,
    float* __restrict__ out)
{
    __shared__ __align__(16) short Abuf[2][32][256];   // 2 x 16KB, write-swizzled
    __shared__ __align__(16) short Hself[16][256];     // 8KB,  write-swizzled
    __shared__ __align__(16) short Hagg[16][264];      // padded
    __shared__ float wsh[16][16];
    __shared__ float nsq_sh[16];

    const int tid  = threadIdx.x;
    const int wave = tid >> 6;
    const int lane = tid & 63;
    const int brow = lane & 15;
    const int kgrp = lane >> 4;
    const int nb_base = blockIdx.x * 16;

    wsh[tid >> 4][tid & 15] = nb_w[nb_base * TNB + tid];
    if (tid < 16) nsq_sh[tid] = 0.f;

    float qb[4], wb[4];
    #pragma unroll
    for (int ni = 0; ni < 4; ++ni) {
        qb[ni] = Qb[wave * 64 + ni * 16 + brow];
        wb[ni] = Wb[wave * 64 + ni * 16 + brow];
    }

    // ---- per-lane staging geometry ----
    const int rl   = wave * 8 + (lane >> 3);   // A-tile row 0..31 this lane stages
    const int sb   = lane & 7;                 // base 16B slot
    auto rowgid = [&](int rnd) {
        int nl = rnd * 2 + (rl >> 4);
        return nb_nodes[(nb_base + nl) * TNB + (rl & 15)];
    };

    // ---- prologue: self rows (once) ----
    {
        const int rl2  = wave * 4 + (lane >> 4);
        const int slot = lane & 15;
        int gs = nodeset[nb_base + rl2];
        const char* srcS = (const char*)hb + ((size_t)gs << 9) + ((size_t)slot << 4);
        short8 s0 = *(const short8*)(srcS);
        short8 s1 = *(const short8*)(srcS + 256);
        char* dstS = (char*)&Hself[0][0] + rl2 * 512 + ((slot ^ (rl2 & 7)) << 4);
        *(short8*)(dstS)       = s0;
        *(short8*)(dstS + 256) = s1;
    }
    // ---- prologue: round-0 rows -> buf0; idx for round 1 in flight ----
    {
        int gA = rowgid(0);
        const char* srcA = (const char*)hb + ((size_t)gA << 9) + ((size_t)sb << 4);
        short8 v0 = *(const short8*)(srcA);
        short8 v1 = *(const short8*)(srcA + 128);
        short8 v2 = *(const short8*)(srcA + 256);
        short8 v3 = *(const short8*)(srcA + 384);
        char* dstA = (char*)&Abuf[0][0][0] + rl * 512 + ((sb ^ (rl & 7)) << 4);
        *(short8*)(dstA)       = v0;
        *(short8*)(dstA + 128) = v1;
        *(short8*)(dstA + 256) = v2;
        *(short8*)(dstA + 384) = v3;
    }
    int gCur = rowgid(1);

    // ---- preload wave's Q B-slice (compiler may re-stream from L2; harmless) ----
    short8 bq[8][4];
    #pragma unroll
    for (int kk = 0; kk < 8; ++kk)
        #pragma unroll
        for (int ni = 0; ni < 4; ++ni)
            bq[kk][ni] = *(const short8*)(
                Qwb + (((size_t)(wave * 64 + ni * 16 + brow)) << 8) + kk * 32 + kgrp * 8);

    __syncthreads();

    #pragma unroll
    for (int rnd = 0; rnd < 8; ++rnd) {
        const int b = rnd & 1;

        // ---- issue next-round staging EARLY (latency hides under GEMM) ----
        int gNext = 0;
        if (rnd < 6) gNext = rowgid(rnd + 2);
        short8 w0, w1, w2, w3;
        if (rnd < 7) {
            const char* srcA = (const char*)hb + ((size_t)gCur << 9) + ((size_t)sb << 4);
            w0 = *(const short8*)(srcA);
            w1 = *(const short8*)(srcA + 128);
            w2 = *(const short8*)(srcA + 256);
            w3 = *(const short8*)(srcA + 384);
        }

        // ---- Q-GEMM: M=32 (2 nodes x 16 t), N=64 (wave slice), K=256 ----
        const char* ab = (const char*)&Abuf[b][0][0];
        f32x4 acc[2][4];
        #pragma unroll
        for (int mi = 0; mi < 2; ++mi)
            #pragma unroll
            for (int ni = 0; ni < 4; ++ni) acc[mi][ni] = (f32x4)0.f;

        #pragma unroll
        for (int kk = 0; kk < 8; ++kk) {
            const int sx = ((kk * 4 + kgrp) ^ (brow & 7)) << 4;
            short8 a0 = *(const short8*)(ab + brow * 512 + sx);
            short8 a1 = *(const short8*)(ab + (16 + brow) * 512 + sx);
            #pragma unroll
            for (int ni = 0; ni < 4; ++ni) {
                acc[0][ni] = __builtin_amdgcn_mfma_f32_16x16x32_bf16(a0, bq[kk][ni], acc[0][ni], 0, 0, 0);
                acc[1][ni] = __builtin_amdgcn_mfma_f32_16x16x32_bf16(a1, bq[kk][ni], acc[1][ni], 0, 0, 0);
            }
        }

        // ---- bias + leaky + weighted agg; D: row=t=(kgrp*4+r), col=ni*16+brow ----
        #pragma unroll
        for (int mi = 0; mi < 2; ++mi) {
            const int nl = rnd * 2 + mi;
            float denom = 0.f;
            #pragma unroll
            for (int t = 0; t < TNB; ++t) denom += wsh[nl][t];
            if (denom == 0.f) denom = 1.f;
            float inv_d = 1.0f / denom;
            float w4[4];
            #pragma unroll
            for (int r = 0; r < 4; ++r) w4[r] = wsh[nl][kgrp * 4 + r];
            #pragma unroll
            for (int ni = 0; ni < 4; ++ni) {
                float pacc = 0.f;
                #pragma unroll
                for (int r = 0; r < 4; ++r) {
                    float v = acc[mi][ni][r] + qb[ni];
                    v = fmaxf(v, SLOPE * v);
                    pacc = fmaf(w4[r], v, pacc);
                }
                pacc += __shfl_xor(pacc, 16, 64);
                pacc += __shfl_xor(pacc, 32, 64);
                if (kgrp == 0) Hagg[nl][wave * 64 + ni * 16 + brow] = f2b(pacc * inv_d);
            }
        }

        // ---- ds_write next-round tile (loads landed during GEMM) ----
        if (rnd < 7) {
            char* dstA = (char*)&Abuf[b ^ 1][0][0] + rl * 512 + ((sb ^ (rl & 7)) << 4);
            *(short8*)(dstA)       = w0;
            *(short8*)(dstA + 128) = w1;
            *(short8*)(dstA + 256) = w2;
            *(short8*)(dstA + 384) = w3;
            gCur = gNext;
        }
        __syncthreads();
    }

    // ---- W-GEMM: M=16 nodes, N=64 (wave slice), K=512 = [self | agg] ----
    f32x4 acc2[4];
    #pragma unroll
    for (int ni = 0; ni < 4; ++ni) acc2[ni] = (f32x4)0.f;

    #pragma unroll
    for (int kk = 0; kk < 8; ++kk) {           // K-half 0: Hself (swizzled)
        const int sx = ((kk * 4 + kgrp) ^ (brow & 7)) << 4;
        short8 a = *(const short8*)((const char*)&Hself[0][0] + brow * 512 + sx);
        #pragma unroll
        for (int ni = 0; ni < 4; ++ni) {
            short8 bb = *(const short8*)(
                Wwb + (((size_t)(wave * 64 + ni * 16 + brow)) << 9) + kk * 32 + kgrp * 8);
            acc2[ni] = __builtin_amdgcn_mfma_f32_16x16x32_bf16(a, bb, acc2[ni], 0, 0, 0);
        }
    }
    #pragma unroll
    for (int kk = 0; kk < 8; ++kk) {           // K-half 1: Hagg (padded)
        short8 a = *(const short8*)(&Hagg[brow][kk * 32 + kgrp * 8]);
        #pragma unroll
        for (int ni = 0; ni < 4; ++ni) {
            short8 bb = *(const short8*)(
                Wwb + (((size_t)(wave * 64 + ni * 16 + brow)) << 9) + 256 + kk * 32 + kgrp * 8);
            acc2[ni] = __builtin_amdgcn_mfma_f32_16x16x32_bf16(a, bb, acc2[ni], 0, 0, 0);
        }
    }

    // ---- bias + leaky + L2 norm + store; D row = node = kgrp*4+r ----
    float vv[4][4];
    float ps[4] = {0.f, 0.f, 0.f, 0.f};
    #pragma unroll
    for (int ni = 0; ni < 4; ++ni)
        #pragma unroll
        for (int r = 0; r < 4; ++r) {
            float v = acc2[ni][r] + wb[ni];
            v = fmaxf(v, SLOPE * v);
            vv[ni][r] = v;
            ps[r] = fmaf(v, v, ps[r]);
        }
    #pragma unroll
    for (int m = 1; m < 16; m <<= 1)
        #pragma unroll
        for (int r = 0; r < 4; ++r) ps[r] += __shfl_xor(ps[r], m, 64);
    if (brow == 0) {
        #pragma unroll
        for (int r = 0; r < 4; ++r) atomicAdd(&nsq_sh[kgrp * 4 + r], ps[r]);
    }
    __syncthreads();

    #pragma unroll
    for (int r = 0; r < 4; ++r) {
        int node = kgrp * 4 + r;
        float nrm = sqrtf(nsq_sh[node]);
        if (nrm == 0.f) nrm = 1.f;
        float inv_n = 1.0f / nrm;
        #pragma unroll
        for (int ni = 0; ni < 4; ++ni)
            out[(size_t)(nb_base + node) * F + wave * 64 + ni * 16 + brow] = vv[ni][r] * inv_n;
    }
}

__global__ void gather_out_kernel(float* __restrict__ out, const float* __restrict__ new1,
                                  const int* __restrict__ map1, const int* __restrict__ nodeset1) {
    int i = blockIdx.x;
    int f = threadIdx.x;
    int w = map1[nodeset1[i]];
    out[(size_t)i * F + f] = new1[(size_t)w * F + f];
}

extern "C" void kernel_launch(void* const* d_in, const int* in_sizes, int n_in,
                              void* d_out, int out_size, void* d_ws, size_t ws_size,
                              hipStream_t stream) {
    const float* h    = (const float*)d_in[0];
    const float* Q0w  = (const float*)d_in[1];
    const float* Q0b  = (const float*)d_in[2];
    const float* W0w  = (const float*)d_in[3];
    const float* W0b  = (const float*)d_in[4];
    const float* Q1w  = (const float*)d_in[5];
    const float* Q1b  = (const float*)d_in[6];
    const float* W1w  = (const float*)d_in[7];
    const float* W1b  = (const float*)d_in[8];
    const float* nbw0 = (const float*)d_in[9];
    const float* nbw1 = (const float*)d_in[10];
    const int* ns0    = (const int*)d_in[11];
    const int* nbn0   = (const int*)d_in[12];
    const int* ns1    = (const int*)d_in[13];
    const int* nbn1   = (const int*)d_in[14];

    const int L0 = in_sizes[11];        // 65536
    const int L1 = in_sizes[13];        // 4096
    const int NN = in_sizes[0] / F;     // 500000

    char* ws = (char*)d_ws;
    short* hb   = (short*)ws; ws += (size_t)NN * F * sizeof(short);   // 256 MB bf16 table
    float* new0 = (float*)ws; ws += (size_t)L0 * F * sizeof(float);   // 64 MB
    float* new1 = (float*)ws; ws += (size_t)L1 * F * sizeof(float);   // 4 MB
    int* map0 = (int*)ws;     ws += (size_t)NN * sizeof(int);
    int* map1 = (int*)ws;     ws += (size_t)NN * sizeof(int);
    short* Q0wb = (short*)ws; ws += (size_t)F * F * sizeof(short);
    short* W0wb = (short*)ws; ws += (size_t)F * 2 * F * sizeof(short);
    short* Q1wb = (short*)ws; ws += (size_t)F * F * sizeof(short);
    short* W1wb = (short*)ws;

    long n8 = (long)NN * F / 8;
    cvt_table_kernel<<<(int)((n8 + 255) / 256), 256, 0, stream>>>(h, hb, n8);
    init_map_kernel<<<(NN + 255) / 256, 256, 0, stream>>>(map0, NN);
    init_map_kernel<<<(NN + 255) / 256, 256, 0, stream>>>(map1, NN);
    build_map_kernel<<<(L0 + 255) / 256, 256, 0, stream>>>(map0, ns0, L0);
    build_map_kernel<<<(L1 + 255) / 256, 256, 0, stream>>>(map1, ns1, L1);
    cvt_bf16_kernel<<<(F * F + 255) / 256, 256, 0, stream>>>(Q0w, Q0wb, F * F);
    cvt_bf16_kernel<<<(F * 2 * F + 255) / 256, 256, 0, stream>>>(W0w, W0wb, F * 2 * F);
    cvt_bf16_kernel<<<(F * F + 255) / 256, 256, 0, stream>>>(Q1w, Q1wb, F * F);
    cvt_bf16_kernel<<<(F * 2 * F + 255) / 256, 256, 0, stream>>>(W1w, W1wb, F * 2 * F);

    conv_mfma_kernel<<<L0 / 16, 256, 0, stream>>>(
        hb, ns0, nbn0, nbw0, Q0wb, Q0b, W0wb, W0b, new0);
    scatter_cvt_kernel<<<(L0 + 3) / 4, 256, 0, stream>>>(new0, ns0, map0, hb, L0);
    conv_mfma_kernel<<<L1 / 16, 256, 0, stream>>>(
        hb, ns1, nbn1, nbw1, Q1wb, Q1b, W1wb, W1b, new1);
    gather_out_kernel<<<L1, 256, 0, stream>>>((float*)d_out, new1, map1, ns1);
}